// Round 8
// baseline (507.960 us; speedup 1.0000x reference)
//
#include <hip/hip_runtime.h>
#include <hip/hip_bf16.h>

typedef float fx4 __attribute__((ext_vector_type(4)));
typedef short i16x8 __attribute__((ext_vector_type(8)));
typedef unsigned short u16;

#define NEG_INF_F (-9.0e15f)

__device__ inline u16 f2bf(float v){
  __hip_bfloat16 h = __float2bfloat16(v);
  return *reinterpret_cast<u16*>(&h);
}

// ---------------------------------------------------------------------------
// Kernel 0: adj (96x512x512 int32, 100.7MB) -> bitmask (3.1MB). Pure stream.
// ---------------------------------------------------------------------------
__global__ __launch_bounds__(256) void gat_compress(
    const int* __restrict__ adj, unsigned* __restrict__ maskw)
{
  const int t = blockIdx.x * 256 + threadIdx.x;
  const uint4* src = (const uint4*)adj + (size_t)t * 8;
  uint4 v[8];
  #pragma unroll
  for (int i = 0; i < 8; ++i) v[i] = src[i];
  unsigned m = 0u;
  #pragma unroll
  for (int i = 0; i < 8; ++i) {
    if ((int)v[i].x > 0) m |= 1u << (4*i+0);
    if ((int)v[i].y > 0) m |= 1u << (4*i+1);
    if ((int)v[i].z > 0) m |= 1u << (4*i+2);
    if ((int)v[i].w > 0) m |= 1u << (4*i+3);
  }
  maskw[t] = m;
}

// ---------------------------------------------------------------------------
// Kernel 1: Wh = x @ W, f1, f2; whB in MFMA B-fragment-linear layout.
// ---------------------------------------------------------------------------
__global__ __launch_bounds__(256) void gat_prep(
    const float* __restrict__ input,   // (8,64,12,512)
    const float* __restrict__ W,       // (64,64)
    const float* __restrict__ Avec,    // (128,1)
    u16*   __restrict__ whB,           // (96,16,4,512) bf16 fragment-linear
    float* __restrict__ f1w,           // (96,512)
    float* __restrict__ f2w)           // (96,512)
{
  __shared__ float Wl[64*64];
  __shared__ float Al[128];
  __shared__ u16   Rp[16384];
  const int tid = threadIdx.x;
  const int bt  = blockIdx.y;
  const int b   = bt / 12, t = bt % 12;
  const int xb  = blockIdx.x;
  const int n   = xb * 256 + tid;

  {
    const fx4* src = (const fx4*)W;
    fx4* dst = (fx4*)Wl;
    #pragma unroll
    for (int i = 0; i < 4; ++i) dst[tid + 256*i] = src[tid + 256*i];
    if (tid < 32) ((fx4*)Al)[tid] = ((const fx4*)Avec)[tid];
  }
  __syncthreads();

  const float* xp = input + ((size_t)b*64*12 + t) * 512 + n;

  fx4 acc[16];
  #pragma unroll
  for (int i = 0; i < 16; ++i) acc[i] = (fx4){0.f,0.f,0.f,0.f};

  #pragma unroll 8
  for (int f = 0; f < 64; ++f) {
    float xv = xp[(size_t)f * 6144];
    const fx4* wr = (const fx4*)(Wl + f*64);
    #pragma unroll
    for (int o4 = 0; o4 < 16; ++o4) acc[o4] += xv * wr[o4];
  }

  float s1 = 0.f, s2 = 0.f;
  #pragma unroll
  for (int o4 = 0; o4 < 16; ++o4) {
    fx4 v  = acc[o4];
    fx4 w1 = ((const fx4*)Al)[o4];
    fx4 w2 = ((const fx4*)Al)[o4 + 16];
    s1 += v[0]*w1[0] + v[1]*w1[1] + v[2]*w1[2] + v[3]*w1[3];
    s2 += v[0]*w2[0] + v[1]*w2[1] + v[2]*w2[2] + v[3]*w2[3];
  }
  f1w[bt*512 + n] = s1;
  f2w[bt*512 + n] = s2;

  const int ktl  = (n >> 5) & 7;
  const int q    = (n >> 3) & 3;
  const int e    = n & 7;
  const int rowb = ktl*2048 + q*128 + e;
  #pragma unroll
  for (int o4 = 0; o4 < 16; ++o4) {
    #pragma unroll
    for (int c = 0; c < 4; ++c) {
      const int o = o4*4 + c;
      Rp[rowb + (o >> 4)*512 + (o & 15)*8] = f2bf(acc[o4][c]);
    }
  }
  __syncthreads();

  uint4* dst = (uint4*)(whB + ((size_t)bt*16 + xb*8) * 2048);
  const uint4* src = (const uint4*)Rp;
  #pragma unroll
  for (int i = 0; i < 8; ++i) dst[tid + 256*i] = src[tid + 256*i];
}

// ---------------------------------------------------------------------------
// Kernel 2 — DIAGNOSTIC build: identical R7 algorithm, but the {phase A ->
// phase B} region re-executes n_rep times (runtime arg; deterministic; output
// stored only on the final rep with identical values). Purpose: push
// gat_attn above the 57us harness fills in the profile and obtain its true
// counters. asm keepalive prevents MFMA DCE on non-final reps (rule #17).
// ---------------------------------------------------------------------------
__global__ __launch_bounds__(256, 4) void gat_attn(
    const unsigned* __restrict__ maskw, // (96,512,16) u32 bitmasks
    const u16*   __restrict__ whB,   // (96,16,4,512) bf16 fragment-linear
    const float* __restrict__ f1w,
    const float* __restrict__ f2w,
    float*       __restrict__ out,   // (96,512,64)
    int n_rep)
{
  __shared__ float f2l[512];
  __shared__ float f1l[16];
  __shared__ float wmaxl[4];
  __shared__ float sums[16];
  __shared__ unsigned maskl[16][16];
  __shared__ u16   attnl[16*512];

  const int tid = threadIdx.x;
  const int l   = tid & 63;
  const int w   = tid >> 6;
  const int bt  = blockIdx.y;
  const int it  = blockIdx.x;

  // ---- one-time stage: masks (1KB), f2 (+max), f1, factor tables ---------
  ((unsigned*)maskl)[tid] = maskw[((size_t)bt*512 + it*16)*16 + tid];
  float2 fv = ((const float2*)(f2w + bt*512))[tid];
  ((float2*)f2l)[tid] = fv;
  float m2 = fmaxf(fv.x, fv.y);
  #pragma unroll
  for (int off = 32; off >= 1; off >>= 1) m2 = fmaxf(m2, __shfl_xor(m2, off));
  if (l == 0) wmaxl[w] = m2;
  if (tid < 16) f1l[tid] = f1w[bt*512 + it*16 + tid];
  __syncthreads();
  const float F2max = fmaxf(fmaxf(wmaxl[0], wmaxl[1]), fmaxf(wmaxl[2], wmaxl[3]));

  const fx4 f20 = ((const fx4*)f2l)[l];
  const fx4 f21 = ((const fx4*)f2l)[64 + l];
  fx4 v0, v1, vh0, vh1;
  #pragma unroll
  for (int c = 0; c < 4; ++c) {
    v0[c]  = __expf(f20[c] - F2max);
    v1[c]  = __expf(f21[c] - F2max);
    vh0[c] = __expf(0.2f*(f20[c] - F2max));
    vh1[c] = __expf(0.2f*(f21[c] - F2max));
  }

  const int R0 = w * 4;
  const int wi = l >> 3;
  const int sh = (l & 7) * 4;

  #pragma unroll 1
  for (int rep = 0; rep < n_rep; ++rep) {
    // ---------------- phase A ----------------------------------------------
    float ssum[4];
    #pragma unroll
    for (int r = 0; r < 4; ++r) {
      const int rowR = R0 + r;
      const unsigned nib0 = (maskl[rowR][wi]     >> sh) & 0xFu;
      const unsigned nib1 = (maskl[rowR][8 + wi] >> sh) & 0xFu;
      const float f1v = f1l[rowR];

      float mx = NEG_INF_F;
      mx = fmaxf(mx, (nib0 & 1u) ? f20[0] : NEG_INF_F);
      mx = fmaxf(mx, (nib0 & 2u) ? f20[1] : NEG_INF_F);
      mx = fmaxf(mx, (nib0 & 4u) ? f20[2] : NEG_INF_F);
      mx = fmaxf(mx, (nib0 & 8u) ? f20[3] : NEG_INF_F);
      mx = fmaxf(mx, (nib1 & 1u) ? f21[0] : NEG_INF_F);
      mx = fmaxf(mx, (nib1 & 2u) ? f21[1] : NEG_INF_F);
      mx = fmaxf(mx, (nib1 & 4u) ? f21[2] : NEG_INF_F);
      mx = fmaxf(mx, (nib1 & 8u) ? f21[3] : NEG_INF_F);
      #pragma unroll
      for (int off = 32; off >= 1; off >>= 1) mx = fmaxf(mx, __shfl_xor(mx, off));

      const float tM = f1v + mx;
      const float M  = fmaxf(tM, 0.2f*tM);
      const float gap = F2max - mx;

      float sum = 0.f;
      ushort4 pk0, pk1;
      if (gap <= 80.f) {
        const float u  = __expf(f1v + F2max - M);
        const float uh = __expf(0.2f*(f1v + F2max) - M);
        const float thr = -f1v;
        float pv;
#define GAT_F(pkf, bb_, ff, vv, vvh) { \
        const bool cpos = (ff) > thr; \
        float a = cpos ? (vv) : (vvh); \
        float bb = cpos ? u : uh; \
        pv = (bb_) ? a*bb : 0.f; sum += pv; pkf = f2bf(pv); }
        GAT_F(pk0.x, nib0 & 1u, f20[0], v0[0], vh0[0])
        GAT_F(pk0.y, nib0 & 2u, f20[1], v0[1], vh0[1])
        GAT_F(pk0.z, nib0 & 4u, f20[2], v0[2], vh0[2])
        GAT_F(pk0.w, nib0 & 8u, f20[3], v0[3], vh0[3])
        GAT_F(pk1.x, nib1 & 1u, f21[0], v1[0], vh1[0])
        GAT_F(pk1.y, nib1 & 2u, f21[1], v1[1], vh1[1])
        GAT_F(pk1.z, nib1 & 4u, f21[2], v1[2], vh1[2])
        GAT_F(pk1.w, nib1 & 8u, f21[3], v1[3], vh1[3])
#undef GAT_F
      } else {
        const float Mf = (mx == NEG_INF_F) ? NEG_INF_F : M;
        float pv;
#define GAT_S(pkf, bb_, ff) { float s = f1v + (ff); float lr = fmaxf(s, 0.2f*s); \
        float ee = (bb_) ? lr : NEG_INF_F; \
        pv = __expf(ee - Mf); sum += pv; pkf = f2bf(pv); }
        GAT_S(pk0.x, nib0 & 1u, f20[0]) GAT_S(pk0.y, nib0 & 2u, f20[1])
        GAT_S(pk0.z, nib0 & 4u, f20[2]) GAT_S(pk0.w, nib0 & 8u, f20[3])
        GAT_S(pk1.x, nib1 & 1u, f21[0]) GAT_S(pk1.y, nib1 & 2u, f21[1])
        GAT_S(pk1.z, nib1 & 4u, f21[2]) GAT_S(pk1.w, nib1 & 8u, f21[3])
#undef GAT_S
      }
      ssum[r] = sum;

      const unsigned swz = (unsigned)((rowR & 7) << 4);
      char* base = (char*)attnl + rowR * 1024;
      *(ushort4*)(base + (((unsigned)(      8*l)) ^ swz)) = pk0;
      *(ushort4*)(base + (((unsigned)(512 + 8*l)) ^ swz)) = pk1;
    }

    #pragma unroll
    for (int r = 0; r < 4; ++r) {
      #pragma unroll
      for (int off = 32; off >= 1; off >>= 1) ssum[r] += __shfl_xor(ssum[r], off);
    }
    if (l == 0) {
      #pragma unroll
      for (int r = 0; r < 4; ++r) sums[R0 + r] = ssum[r];
    }
    __syncthreads();

    // ---------------- phase B ----------------------------------------------
    {
      const int r = l & 15, q = l >> 4;
      const int ct = w;
      const unsigned swzB = (unsigned)((r & 7) << 4);
      const char* aBase = (const char*)attnl + r * 1024;
      const u16*  wp    = whB + (size_t)bt*32768 + ct*512 + l*8;
      fx4 acc = {0,0,0,0};

      #pragma unroll
      for (int kt = 0; kt < 16; ++kt) {
        i16x8 af = *(const i16x8*)(aBase + (((unsigned)(kt*64 + q*16)) ^ swzB));
        i16x8 bf = *(const i16x8*)(wp + kt*2048);
        acc = __builtin_amdgcn_mfma_f32_16x16x32_bf16(af, bf, acc, 0, 0, 0);
      }
      // keep MFMA live on non-final reps (rule #17)
      asm volatile("" :: "v"(acc[0]), "v"(acc[1]), "v"(acc[2]), "v"(acc[3]));

      if (rep == n_rep - 1) {
        float* op = out + ((size_t)bt*512 + it*16) * 64;
        #pragma unroll
        for (int rr = 0; rr < 4; ++rr) {
          const float rs = 1.0f / sums[q*4 + rr];
          float v = acc[rr] * rs;
          v = v > 0.f ? v : expm1f(v);
          op[(q*4 + rr)*64 + ct*16 + r] = v;
        }
      }
    }
    __syncthreads();   // attnl/sums safe to rewrite next rep
  }
}

// ---------------------------------------------------------------------------
extern "C" void kernel_launch(void* const* d_in, const int* in_sizes, int n_in,
                              void* d_out, int out_size, void* d_ws, size_t ws_size,
                              hipStream_t stream) {
  const float* input = (const float*)d_in[0];   // (8,64,12,512) f32
  const int*   adj   = (const int*)  d_in[1];   // (8,12,512,512) i32
  const float* W     = (const float*)d_in[2];   // (64,64) f32
  const float* Avec  = (const float*)d_in[3];   // (128,1) f32
  float* out = (float*)d_out;

  // ws: whB bf16 (6,291,456 B) | f1 (196,608) | f2 (196,608) | mask (3,145,728)
  char* ws = (char*)d_ws;
  u16*      whB   = (u16*)ws;
  float*    f1w   = (float*)(ws + 6291456);
  float*    f2w   = (float*)(ws + 6291456 + 196608);
  unsigned* maskw = (unsigned*)(ws + 6291456 + 393216);

  gat_compress<<<3072, 256, 0, stream>>>(adj, maskw);
  gat_prep<<<dim3(2, 96), 256, 0, stream>>>(input, W, Avec, whB, f1w, f2w);
  gat_attn<<<dim3(32, 96), 256, 0, stream>>>(maskw, whB, f1w, f2w, out, 32);
}

// Round 9
// 51.352 us; speedup vs baseline: 9.8917x; 9.8917x over previous
//
#include <hip/hip_runtime.h>
#include <hip/hip_bf16.h>

typedef float fx4 __attribute__((ext_vector_type(4)));
typedef short i16x8 __attribute__((ext_vector_type(8)));
typedef unsigned short u16;

#define NEG_INF_F (-9.0e15f)

__device__ inline u16 f2bf(float v){
  __hip_bfloat16 h = __float2bfloat16(v);
  return *reinterpret_cast<u16*>(&h);
}
__device__ inline unsigned pk2(float lo, float hi){
  return (unsigned)f2bf(lo) | ((unsigned)f2bf(hi) << 16);
}

// ---------------------------------------------------------------------------
// Kernel A (fused): blocks 0..191 = prep (Wh/f1/f2/whB), blocks 192.. = adj
// bitmask compress. Independent work; fusion overlaps prep compute with the
// compress HBM stream and saves a launch gap.
// ---------------------------------------------------------------------------
__global__ __launch_bounds__(256) void gat_pre(
    const float* __restrict__ input,   // (8,64,12,512)
    const float* __restrict__ W,       // (64,64)
    const float* __restrict__ Avec,    // (128,1)
    const int*   __restrict__ adj,     // (96,512,512)
    u16*      __restrict__ whB,        // (96,16,4,512) bf16 fragment-linear
    float*    __restrict__ f1w,        // (96,512)
    float*    __restrict__ f2w,        // (96,512)
    unsigned* __restrict__ maskw)      // (96*512*16)
{
  __shared__ float Wl[64*64];
  __shared__ float Al[128];
  __shared__ u16   Rp[16384];
  const int bid = blockIdx.x;
  const int tid = threadIdx.x;

  if (bid >= 192) {
    // ---- compress: 100.7MB int32 -> 3.1MB bitmask, pure stream ----------
    const int t = (bid - 192) * 256 + tid;
    const uint4* src = (const uint4*)adj + (size_t)t * 8;
    uint4 v[8];
    #pragma unroll
    for (int i = 0; i < 8; ++i) v[i] = src[i];
    unsigned m = 0u;
    #pragma unroll
    for (int i = 0; i < 8; ++i) {
      if ((int)v[i].x > 0) m |= 1u << (4*i+0);
      if ((int)v[i].y > 0) m |= 1u << (4*i+1);
      if ((int)v[i].z > 0) m |= 1u << (4*i+2);
      if ((int)v[i].w > 0) m |= 1u << (4*i+3);
    }
    maskw[t] = m;
    return;
  }

  // ---- prep: Wh = x@W, f1, f2, whB fragment-linear ----------------------
  const int bt = bid >> 1, xb = bid & 1;
  const int b  = bt / 12, t = bt % 12;
  const int n  = xb * 256 + tid;

  {
    const fx4* src = (const fx4*)W;
    fx4* dst = (fx4*)Wl;
    #pragma unroll
    for (int i = 0; i < 4; ++i) dst[tid + 256*i] = src[tid + 256*i];
    if (tid < 32) ((fx4*)Al)[tid] = ((const fx4*)Avec)[tid];
  }
  __syncthreads();

  const float* xp = input + ((size_t)b*64*12 + t) * 512 + n;

  fx4 acc[16];
  #pragma unroll
  for (int i = 0; i < 16; ++i) acc[i] = (fx4){0.f,0.f,0.f,0.f};

  #pragma unroll 8
  for (int f = 0; f < 64; ++f) {
    float xv = xp[(size_t)f * 6144];
    const fx4* wr = (const fx4*)(Wl + f*64);
    #pragma unroll
    for (int o4 = 0; o4 < 16; ++o4) acc[o4] += xv * wr[o4];
  }

  float s1 = 0.f, s2 = 0.f;
  #pragma unroll
  for (int o4 = 0; o4 < 16; ++o4) {
    fx4 v  = acc[o4];
    fx4 w1 = ((const fx4*)Al)[o4];
    fx4 w2 = ((const fx4*)Al)[o4 + 16];
    s1 += v[0]*w1[0] + v[1]*w1[1] + v[2]*w1[2] + v[3]*w1[3];
    s2 += v[0]*w2[0] + v[1]*w2[1] + v[2]*w2[2] + v[3]*w2[3];
  }
  f1w[bt*512 + n] = s1;
  f2w[bt*512 + n] = s2;

  const int ktl  = (n >> 5) & 7;
  const int q    = (n >> 3) & 3;
  const int e    = n & 7;
  const int rowb = ktl*2048 + q*128 + e;
  #pragma unroll
  for (int o4 = 0; o4 < 16; ++o4) {
    #pragma unroll
    for (int c = 0; c < 4; ++c) {
      const int o = o4*4 + c;
      Rp[rowb + (o >> 4)*512 + (o & 15)*8] = f2bf(acc[o4][c]);
    }
  }
  __syncthreads();

  uint4* dst = (uint4*)(whB + ((size_t)bt*16 + xb*8) * 2048);
  const uint4* src = (const uint4*)Rp;
  #pragma unroll
  for (int i = 0; i < 8; ++i) dst[tid + 256*i] = src[tid + 256*i];
}

// ---------------------------------------------------------------------------
// Kernel B: masked softmax + PV(MFMA) + ELU.  grid (32,96), 4 waves.
// Phase A fast path per entry: p = max(u*v_j, uh*vh_j)  [exact: exp/monotone
// algebra of lrelu], masking via bf16-domain AND with a nibble->mask LUT,
// NO per-entry exp/select/sum.  Row sums computed by wave 0 in phase B via a
// parallel MFMA chain with B = ones (reuses A-fragments).  Rows failing the
// underflow-safety test (incl. all-masked rows) take the exact-exp path.
// ---------------------------------------------------------------------------
__global__ __launch_bounds__(256, 4) void gat_attn(
    const unsigned* __restrict__ maskw, // (96,512,16) u32 bitmasks
    const u16*   __restrict__ whB,   // (96,16,4,512) bf16 fragment-linear
    const float* __restrict__ f1w,
    const float* __restrict__ f2w,
    float*       __restrict__ out)   // (96,512,64)
{
  __shared__ float f1l[16];
  __shared__ float wmaxl[4];
  __shared__ float sums[16];
  __shared__ unsigned maskl[16][16];
  __shared__ uint2 lutl[16];
  __shared__ u16   attnl[16*512];    // unnormalized p, bf16, XOR-swizzled

  const int tid = threadIdx.x;
  const int l   = tid & 63;
  const int w   = tid >> 6;
  const int bt  = blockIdx.y;
  const int it  = blockIdx.x;

  // ---- stage: masks, f1, LUT; lane-resident f2 + block max ---------------
  ((unsigned*)maskl)[tid] = maskw[((size_t)bt*512 + it*16)*16 + tid];
  if (tid < 16) f1l[tid] = f1w[bt*512 + it*16 + tid];
  if (tid < 16) {
    const unsigned nb = tid;
    lutl[tid] = (uint2){ ((nb&1u)?0xFFFFu:0u) | ((nb&2u)?0xFFFF0000u:0u),
                         ((nb&4u)?0xFFFFu:0u) | ((nb&8u)?0xFFFF0000u:0u) };
  }
  const float* f2p = f2w + bt*512;
  const fx4 f20 = ((const fx4*)f2p)[l];        // j = 4l .. 4l+3
  const fx4 f21 = ((const fx4*)f2p)[64 + l];   // j = 256+4l ..
  float m2 = fmaxf(fmaxf(fmaxf(f20[0], f20[1]), fmaxf(f20[2], f20[3])),
                   fmaxf(fmaxf(f21[0], f21[1]), fmaxf(f21[2], f21[3])));
  #pragma unroll
  for (int off = 32; off >= 1; off >>= 1) m2 = fmaxf(m2, __shfl_xor(m2, off));
  if (l == 0) wmaxl[w] = m2;
  __syncthreads();
  const float F2max = fmaxf(fmaxf(wmaxl[0], wmaxl[1]), fmaxf(wmaxl[2], wmaxl[3]));

  // factor tables (16 exps, one-time) + safety bit pattern
  fx4 v0, v1, vh0, vh1;
  #pragma unroll
  for (int c = 0; c < 4; ++c) {
    v0[c]  = __expf(f20[c] - F2max);
    v1[c]  = __expf(f21[c] - F2max);
    vh0[c] = __expf(0.2f*(f20[c] - F2max));
    vh1[c] = __expf(0.2f*(f21[c] - F2max));
  }
  const float thrBig = F2max - 80.f;
  const unsigned big_lo = (f20[0] > thrBig ? 1u : 0u) | (f20[1] > thrBig ? 2u : 0u)
                        | (f20[2] > thrBig ? 4u : 0u) | (f20[3] > thrBig ? 8u : 0u);
  const unsigned big_hi = (f21[0] > thrBig ? 1u : 0u) | (f21[1] > thrBig ? 2u : 0u)
                        | (f21[2] > thrBig ? 4u : 0u) | (f21[3] > thrBig ? 8u : 0u);

  // ---------------- phase A ------------------------------------------------
  const int R0 = w * 4;
  const int wi = l >> 3;             // mask word index within half-row
  const int sh = (l & 7) * 4;        // nibble shift

  #pragma unroll
  for (int r = 0; r < 4; ++r) {
    const int rowR = R0 + r;
    const unsigned nib0 = (maskl[rowR][wi]     >> sh) & 0xFu;
    const unsigned nib1 = (maskl[rowR][8 + wi] >> sh) & 0xFu;
    const float f1v = f1l[rowR];

    unsigned w0, w1, w2, w3;
    const unsigned sb = (nib0 & big_lo) | (nib1 & big_hi);
    if (__builtin_expect(__any((int)sb), 1)) {
      // ---- fast path: p = max(u*v, uh*vh), mask by AND after pack --------
      const float tR = f1v + F2max;
      const float M  = fmaxf(tR, 0.2f*tR);
      const float u  = __expf(tR - M);          // 1 when tR>0
      const float uh = __expf(0.2f*tR - M);     // 1 when tR<=0
      fx4 PA, PB;
      #pragma unroll
      for (int c = 0; c < 4; ++c) {
        PA[c] = fmaxf(u*v0[c], uh*vh0[c]);
        PB[c] = fmaxf(u*v1[c], uh*vh1[c]);
      }
      const uint2 mA = lutl[nib0];
      const uint2 mB = lutl[nib1];
      w0 = pk2(PA[0], PA[1]) & mA.x;
      w1 = pk2(PA[2], PA[3]) & mA.y;
      w2 = pk2(PB[0], PB[1]) & mB.x;
      w3 = pk2(PB[2], PB[3]) & mB.y;
    } else {
      // ---- exact path (rare; also all-masked rows -> uniform p=1) --------
      float mx = NEG_INF_F;
      mx = fmaxf(mx, (nib0 & 1u) ? f20[0] : NEG_INF_F);
      mx = fmaxf(mx, (nib0 & 2u) ? f20[1] : NEG_INF_F);
      mx = fmaxf(mx, (nib0 & 4u) ? f20[2] : NEG_INF_F);
      mx = fmaxf(mx, (nib0 & 8u) ? f20[3] : NEG_INF_F);
      mx = fmaxf(mx, (nib1 & 1u) ? f21[0] : NEG_INF_F);
      mx = fmaxf(mx, (nib1 & 2u) ? f21[1] : NEG_INF_F);
      mx = fmaxf(mx, (nib1 & 4u) ? f21[2] : NEG_INF_F);
      mx = fmaxf(mx, (nib1 & 8u) ? f21[3] : NEG_INF_F);
      #pragma unroll
      for (int off = 32; off >= 1; off >>= 1) mx = fmaxf(mx, __shfl_xor(mx, off));
      const float tM = f1v + mx;
      const float Mc = fmaxf(tM, 0.2f*tM);
      const float Mf = (mx == NEG_INF_F) ? NEG_INF_F : Mc;
      float pv[8];
#define GAT_S(idx, bb_, ff) { float s = f1v + (ff); float lr = fmaxf(s, 0.2f*s); \
      float ee = (bb_) ? lr : NEG_INF_F; pv[idx] = __expf(ee - Mf); }
      GAT_S(0, nib0 & 1u, f20[0]) GAT_S(1, nib0 & 2u, f20[1])
      GAT_S(2, nib0 & 4u, f20[2]) GAT_S(3, nib0 & 8u, f20[3])
      GAT_S(4, nib1 & 1u, f21[0]) GAT_S(5, nib1 & 2u, f21[1])
      GAT_S(6, nib1 & 4u, f21[2]) GAT_S(7, nib1 & 8u, f21[3])
#undef GAT_S
      w0 = pk2(pv[0], pv[1]); w1 = pk2(pv[2], pv[3]);
      w2 = pk2(pv[4], pv[5]); w3 = pk2(pv[6], pv[7]);
    }

    const unsigned swz = (unsigned)((rowR & 7) << 4);
    char* base = (char*)attnl + rowR * 1024;
    *(uint2*)(base + (((unsigned)(      8*l)) ^ swz)) = (uint2){w0, w1};
    *(uint2*)(base + (((unsigned)(512 + 8*l)) ^ swz)) = (uint2){w2, w3};
  }
  __syncthreads();

  // ---------------- phase B: MFMA PV (+ ones-sums on wave 0) --------------
  const int r = l & 15, q = l >> 4;
  const unsigned swzB = (unsigned)((r & 7) << 4);
  const char* aBase = (const char*)attnl + r * 1024;
  const u16*  wp    = whB + (size_t)bt*32768 + w*512 + l*8;
  i16x8 bones;
  #pragma unroll
  for (int e = 0; e < 8; ++e) bones[e] = (short)0x3F80;  // bf16 1.0
  fx4 acc = {0,0,0,0}, accS = {0,0,0,0};

  #pragma unroll
  for (int kt = 0; kt < 16; ++kt) {
    i16x8 af = *(const i16x8*)(aBase + (((unsigned)(kt*64 + q*16)) ^ swzB));
    i16x8 bf = *(const i16x8*)(wp + kt*2048);
    acc = __builtin_amdgcn_mfma_f32_16x16x32_bf16(af, bf, acc, 0, 0, 0);
    if (w == 0)
      accS = __builtin_amdgcn_mfma_f32_16x16x32_bf16(af, bones, accS, 0, 0, 0);
  }
  if (w == 0 && r == 0) {
    #pragma unroll
    for (int rr = 0; rr < 4; ++rr) sums[q*4 + rr] = accS[rr];
  }
  __syncthreads();

  // epilogue: normalize + ELU.  C/D layout: col = l&15, row = q*4 + rr
  float* op = out + ((size_t)bt*512 + it*16) * 64;
  #pragma unroll
  for (int rr = 0; rr < 4; ++rr) {
    const float rs = 1.0f / sums[q*4 + rr];
    float v = acc[rr] * rs;
    v = v > 0.f ? v : expm1f(v);
    op[(q*4 + rr)*64 + w*16 + r] = v;
  }
}

// ---------------------------------------------------------------------------
extern "C" void kernel_launch(void* const* d_in, const int* in_sizes, int n_in,
                              void* d_out, int out_size, void* d_ws, size_t ws_size,
                              hipStream_t stream) {
  const float* input = (const float*)d_in[0];   // (8,64,12,512) f32
  const int*   adj   = (const int*)  d_in[1];   // (8,12,512,512) i32
  const float* W     = (const float*)d_in[2];   // (64,64) f32
  const float* Avec  = (const float*)d_in[3];   // (128,1) f32
  float* out = (float*)d_out;

  // ws: whB bf16 (6,291,456 B) | f1 (196,608) | f2 (196,608) | mask (3,145,728)
  char* ws = (char*)d_ws;
  u16*      whB   = (u16*)ws;
  float*    f1w   = (float*)(ws + 6291456);
  float*    f2w   = (float*)(ws + 6291456 + 196608);
  unsigned* maskw = (unsigned*)(ws + 6291456 + 393216);

  gat_pre<<<192 + 3072, 256, 0, stream>>>(input, W, Avec, adj,
                                          whB, f1w, f2w, maskw);
  gat_attn<<<dim3(32, 96), 256, 0, stream>>>(maskw, whB, f1w, f2w, out);
}